// Round 1
// baseline (45.447 us; speedup 1.0000x reference)
//
#include <hip/hip_runtime.h>
#include <math.h>

#define NB 1024
#define NC 64
#define NH 64
#define ND 256
#define NHID 256

// mask storage modes: 0 = int32, 1 = byte (bool), 2 = float32
__device__ __forceinline__ bool read_mask(const void* m, int idx, int mode) {
  if (mode == 2) return ((const float*)m)[idx] != 0.0f;
  if (mode == 1) return ((const unsigned char*)m)[idx] != 0;
  return ((const int*)m)[idx] != 0;
}

// ws layout: ws[0..255] = v_h (float), ws[256] = mask mode (int)
__global__ __launch_bounds__(1024) void precompute_kernel(
    const float* __restrict__ W1, const float* __restrict__ W2,
    const unsigned int* __restrict__ mask_cand,
    const unsigned int* __restrict__ mask_hist,
    float* __restrict__ ws)
{
  __shared__ float w2_lds[NHID];
  __shared__ float partial[4][ND];
  int t = threadIdx.x;
  if (t < NHID) w2_lds[t] = W2[t];
  __syncthreads();
  int d = t & (ND - 1);
  int g = t >> 8;                      // 0..3, each group covers 64 j's
  float acc = 0.f;
  #pragma unroll 8
  for (int j = g * 64; j < g * 64 + 64; ++j)
    acc = fmaf(W1[(size_t)j * (2 * ND) + ND + d], w2_lds[j], acc);
  partial[g][d] = acc;
  __syncthreads();
  if (t < ND)
    ws[t] = partial[0][t] + partial[1][t] + partial[2][t] + partial[3][t];
  if (t == 0) {
    // Detect how the boolean masks were materialized on device.
    // int32 storage: every 4-byte word is 0 or 1.
    // byte-bool storage: words pack 4 bools -> some word has a high byte set.
    // float32 storage: words are 0 or 0x3f800000.
    int sawf = 0; unsigned int big = 0;
    for (int i = 0; i < 32; ++i) {
      unsigned int a = mask_hist[i], b = mask_cand[i];
      if (a == 0x3f800000u || b == 0x3f800000u) sawf = 1;
      if ((a > 1u && a != 0x3f800000u) || (b > 1u && b != 0x3f800000u)) big = 1;
    }
    ((int*)ws)[ND] = sawf ? 2 : (big ? 1 : 0);
  }
}

__global__ __launch_bounds__(256) void user_encoder_kernel(
    const float* __restrict__ hist,
    const void* __restrict__ mask_cand_v,
    const void* __restrict__ mask_hist_v,
    const float* __restrict__ ws,
    float* __restrict__ out)
{
  const int b = blockIdx.x;
  const int t = threadIdx.x;
  const int wave = t >> 6;
  const int lane = t & 63;

  __shared__ float s_lds[NH];        // masked scores
  __shared__ float w_lds[NH];        // softmax weights
  __shared__ float4 part[4][64];     // per-wave partial uv
  __shared__ float4 uv_lds[64];      // final uv as float4

  const int mode = ((const int*)ws)[ND];
  const float* hb = hist + (size_t)b * NH * ND;

  // ---- load this thread's slice of hist[b] ONCE into registers ----
  // thread (wave, lane) holds rows h = wave*16+hh, float4 column `lane`
  float4 xs[16];
  #pragma unroll
  for (int hh = 0; hh < 16; ++hh)
    xs[hh] = reinterpret_cast<const float4*>(hb + (size_t)(wave * 16 + hh) * ND)[lane];

  // ---- phase 1: s_h[h] = dot(hist[h,:], v_h), masked ----
  const float4 vh4 = reinterpret_cast<const float4*>(ws)[lane];
  #pragma unroll
  for (int hh = 0; hh < 16; ++hh) {
    float4 x = xs[hh];
    float p = fmaf(x.x, vh4.x, fmaf(x.y, vh4.y, fmaf(x.z, vh4.z, x.w * vh4.w)));
    #pragma unroll
    for (int off = 32; off; off >>= 1) p += __shfl_xor(p, off);
    if (lane == 0) {
      int h = wave * 16 + hh;
      bool mh = read_mask(mask_hist_v, b * NH + h, mode);
      s_lds[h] = mh ? p : -3.0e38f;
    }
  }
  __syncthreads();

  // ---- phase 2: softmax over H=64, done by wave 0 ----
  if (wave == 0) {
    float s = s_lds[lane];
    float m = s;
    #pragma unroll
    for (int off = 32; off; off >>= 1) m = fmaxf(m, __shfl_xor(m, off));
    float e = expf(s - m);            // masked rows: expf(-3e38 - m) underflows to 0
    float sum = e;
    #pragma unroll
    for (int off = 32; off; off >>= 1) sum += __shfl_xor(sum, off);
    w_lds[lane] = e / sum;
  }
  __syncthreads();

  // ---- phase 3: uv[d] = sum_h w[h] * hist[h,d], from registers ----
  float4 acc = {0.f, 0.f, 0.f, 0.f};
  #pragma unroll
  for (int hh = 0; hh < 16; ++hh) {
    float wgt = w_lds[wave * 16 + hh];
    float4 x = xs[hh];
    acc.x = fmaf(wgt, x.x, acc.x);
    acc.y = fmaf(wgt, x.y, acc.y);
    acc.z = fmaf(wgt, x.z, acc.z);
    acc.w = fmaf(wgt, x.w, acc.w);
  }
  part[wave][lane] = acc;
  __syncthreads();
  if (t < 64) {
    float4 a = part[0][t], b4 = part[1][t], c4 = part[2][t], d4 = part[3][t];
    float4 s4;
    s4.x = a.x + b4.x + c4.x + d4.x;
    s4.y = a.y + b4.y + c4.y + d4.y;
    s4.z = a.z + b4.z + c4.z + d4.z;
    s4.w = a.w + b4.w + c4.w + d4.w;
    uv_lds[t] = s4;
  }
  __syncthreads();

  // ---- phase 4: out[b,c,:] = mask_cand[b,c] ? uv : 0 (vectorized stores) ----
  float4* ob = reinterpret_cast<float4*>(out + (size_t)b * NC * ND);
  const float4 val = uv_lds[lane];
  const float4 zero = {0.f, 0.f, 0.f, 0.f};
  #pragma unroll
  for (int k = 0; k < 16; ++k) {
    int c = k * 4 + wave;                       // uniform within the wave
    bool mc = read_mask(mask_cand_v, b * NC + c, mode);
    ob[k * 256 + t] = mc ? val : zero;
  }
}

extern "C" void kernel_launch(void* const* d_in, const int* in_sizes, int n_in,
                              void* d_out, int out_size, void* d_ws, size_t ws_size,
                              hipStream_t stream) {
  (void)in_sizes; (void)n_in; (void)out_size; (void)ws_size;
  // inputs (setup_inputs order):
  // 0 candidate_news_vector [B,C,D]  (UNUSED: softmax is shift-invariant, the
  //                                   candidate term is a per-row additive constant)
  // 1 clicked_news_vector   [B,H,D]
  // 2 mask_cand [B,C]   3 mask_hist [B,H]
  // 4 W1 [HID, 2D]   5 b1 [HID] (unused)   6 W2 [1,HID]   7 b2 [1] (unused)
  const float* hist = (const float*)d_in[1];
  const void*  mask_cand = d_in[2];
  const void*  mask_hist = d_in[3];
  const float* W1 = (const float*)d_in[4];
  const float* W2 = (const float*)d_in[6];
  float* ws = (float*)d_ws;
  float* out = (float*)d_out;

  precompute_kernel<<<1, 1024, 0, stream>>>(
      W1, W2, (const unsigned int*)mask_cand, (const unsigned int*)mask_hist, ws);
  user_encoder_kernel<<<NB, 256, 0, stream>>>(hist, mask_cand, mask_hist, ws, out);
}

// Round 3
// 43.576 us; speedup vs baseline: 1.0429x; 1.0429x over previous
//
#include <hip/hip_runtime.h>
#include <math.h>

#define NB 1024
#define NC 64
#define NH 64
#define ND 256
#define NHID 256

typedef float f4 __attribute__((ext_vector_type(4)));

// ws layout (floats): [0..255] = v_h, [256] = mask mode (int),
//                     [1024 .. 1024+64*256) = P1 partials (needs ws >= 69632 B)
#define WS_PART_OFF 1024

// mask storage modes: 0 = int32, 1 = byte (bool), 2 = float32
__device__ __forceinline__ bool read_mask(const void* m, int idx, int mode) {
  if (mode == 2) return ((const float*)m)[idx] != 0.0f;
  if (mode == 1) return ((const unsigned char*)m)[idx] != 0;
  return ((const int*)m)[idx] != 0;
}

__device__ __forceinline__ void detect_mode(const unsigned int* mask_cand,
                                            const unsigned int* mask_hist,
                                            int* dst) {
  int sawf = 0; unsigned int big = 0;
  for (int i = 0; i < 32; ++i) {
    unsigned int a = mask_hist[i], b = mask_cand[i];
    if (a == 0x3f800000u || b == 0x3f800000u) sawf = 1;
    if ((a > 1u && a != 0x3f800000u) || (b > 1u && b != 0x3f800000u)) big = 1;
  }
  *dst = sawf ? 2 : (big ? 1 : 0);
}

// ---- P1: 64 blocks x 256 threads: partial v_h over 4 j-rows each ----
__global__ __launch_bounds__(256) void precompute_p1(
    const float* __restrict__ W1, const float* __restrict__ W2,
    float* __restrict__ ws)
{
  const int g = blockIdx.x;          // 0..63, rows j in [4g, 4g+4)
  const int d = threadIdx.x;         // 0..255
  float acc = 0.f;
  #pragma unroll
  for (int jj = 0; jj < 4; ++jj) {
    int j = g * 4 + jj;
    acc = fmaf(W1[(size_t)j * (2 * ND) + ND + d], W2[j], acc);
  }
  ws[WS_PART_OFF + g * ND + d] = acc;
}

// ---- P2: 1 block x 256 threads: reduce partials, detect mask mode ----
__global__ __launch_bounds__(256) void precompute_p2(
    const unsigned int* __restrict__ mask_cand,
    const unsigned int* __restrict__ mask_hist,
    float* __restrict__ ws)
{
  const int d = threadIdx.x;
  float acc = 0.f;
  #pragma unroll 8
  for (int g = 0; g < 64; ++g) acc += ws[WS_PART_OFF + g * ND + d];
  ws[d] = acc;
  if (d == 0) detect_mode(mask_cand, mask_hist, (int*)ws + ND);
}

// ---- fallback single-block precompute (small ws) ----
__global__ __launch_bounds__(1024) void precompute_fallback(
    const float* __restrict__ W1, const float* __restrict__ W2,
    const unsigned int* __restrict__ mask_cand,
    const unsigned int* __restrict__ mask_hist,
    float* __restrict__ ws)
{
  __shared__ float w2_lds[NHID];
  __shared__ float partial[4][ND];
  int t = threadIdx.x;
  if (t < NHID) w2_lds[t] = W2[t];
  __syncthreads();
  int d = t & (ND - 1);
  int g = t >> 8;
  float acc = 0.f;
  #pragma unroll 8
  for (int j = g * 64; j < g * 64 + 64; ++j)
    acc = fmaf(W1[(size_t)j * (2 * ND) + ND + d], w2_lds[j], acc);
  partial[g][d] = acc;
  __syncthreads();
  if (t < ND)
    ws[t] = partial[0][t] + partial[1][t] + partial[2][t] + partial[3][t];
  if (t == 0) detect_mode(mask_cand, mask_hist, (int*)ws + ND);
}

// ---- main: one block (512 thr = 8 waves) per batch b ----
__global__ __launch_bounds__(512, 8) void user_encoder_kernel(
    const float* __restrict__ hist,
    const void* __restrict__ mask_cand_v,
    const void* __restrict__ mask_hist_v,
    const float* __restrict__ ws,
    float* __restrict__ out)
{
  const int b = blockIdx.x;
  const int t = threadIdx.x;
  const int lane = t & 63;
  const int w = t >> 6;              // wave id 0..7

  __shared__ float s_lds[NH];
  __shared__ float4 part[8][64];     // 8 KB

  const int mode = ((const int*)ws)[ND];
  const float4* hb4 = reinterpret_cast<const float4*>(hist + (size_t)b * NH * ND);
  const float4* vh4p = reinterpret_cast<const float4*>(ws);  // L1-hot, same 1KB for all blocks

  // ---- phase 1: s[r] = dot(hist[b,r,:], v_h). thread (r = t>>3, cg = t&7)
  // covers 8 float4 of row r at columns i*8+cg (128B-coalesced per 8 lanes).
  {
    const int r = t >> 3, cg = t & 7;
    float p = 0.f;
    #pragma unroll
    for (int i = 0; i < 8; ++i) {
      float4 x = hb4[r * 64 + i * 8 + cg];
      float4 v = vh4p[i * 8 + cg];
      p = fmaf(x.x, v.x, fmaf(x.y, v.y, fmaf(x.z, v.z, fmaf(x.w, v.w, p))));
    }
    p += __shfl_xor(p, 1); p += __shfl_xor(p, 2); p += __shfl_xor(p, 4);
    if (cg == 0)
      s_lds[r] = read_mask(mask_hist_v, b * NH + r, mode) ? p : -3.0e38f;
  }
  __syncthreads();

  // ---- phase 2: softmax over H=64, computed redundantly by EVERY wave
  // (no second barrier; weights live in registers, fetched via shfl).
  float wval;
  {
    float s = s_lds[lane];
    float m = s;
    #pragma unroll
    for (int off = 32; off; off >>= 1) m = fmaxf(m, __shfl_xor(m, off));
    float e = expf(s - m);           // masked rows underflow to 0
    float sum = e;
    #pragma unroll
    for (int off = 32; off; off >>= 1) sum += __shfl_xor(sum, off);
    wval = e / sum;                  // weight for h = lane
  }

  // ---- phase 3: uv partial. wave w owns rows w*8..w*8+7; lane = float4 col.
  // Re-reads hist[b] (64 KB) from L2/L3 — off the HBM critical path.
  {
    float4 acc = {0.f, 0.f, 0.f, 0.f};
    #pragma unroll
    for (int j = 0; j < 8; ++j) {
      float wj = __shfl(wval, (w << 3) | j);   // broadcast w[h], h = w*8+j
      float4 x = hb4[((w << 3) | j) * 64 + lane];
      acc.x = fmaf(wj, x.x, acc.x);
      acc.y = fmaf(wj, x.y, acc.y);
      acc.z = fmaf(wj, x.z, acc.z);
      acc.w = fmaf(wj, x.w, acc.w);
    }
    part[w][lane] = acc;
  }
  __syncthreads();

  // ---- phase 4: every thread redundantly sums the 8 partials for its lane,
  // then writes 8 output rows (c = w + 8k, uniform per wave, 1KB coalesced).
  {
    float4 uv = part[0][lane];
    #pragma unroll
    for (int g = 1; g < 8; ++g) {
      float4 q = part[g][lane];
      uv.x += q.x; uv.y += q.y; uv.z += q.z; uv.w += q.w;
    }
    float4* ob4 = reinterpret_cast<float4*>(out + (size_t)b * NC * ND);
    #pragma unroll
    for (int k = 0; k < 8; ++k) {
      int c = w + k * 8;
      bool mc = read_mask(mask_cand_v, b * NC + c, mode);
      f4 val = mc ? (f4){uv.x, uv.y, uv.z, uv.w} : (f4){0.f, 0.f, 0.f, 0.f};
      __builtin_nontemporal_store(val, reinterpret_cast<f4*>(&ob4[c * 64 + lane]));
    }
  }
}

extern "C" void kernel_launch(void* const* d_in, const int* in_sizes, int n_in,
                              void* d_out, int out_size, void* d_ws, size_t ws_size,
                              hipStream_t stream) {
  (void)in_sizes; (void)n_in; (void)out_size;
  // inputs: 0 cand [B,C,D] (UNUSED — softmax shift-invariance kills the
  // candidate term), 1 hist [B,H,D], 2 mask_cand, 3 mask_hist,
  // 4 W1 [HID,2D], 5 b1 (unused), 6 W2 [1,HID], 7 b2 (unused)
  const float* hist = (const float*)d_in[1];
  const void*  mask_cand = d_in[2];
  const void*  mask_hist = d_in[3];
  const float* W1 = (const float*)d_in[4];
  const float* W2 = (const float*)d_in[6];
  float* ws = (float*)d_ws;
  float* out = (float*)d_out;

  if (ws_size >= (size_t)(WS_PART_OFF + 64 * ND) * sizeof(float)) {
    precompute_p1<<<64, 256, 0, stream>>>(W1, W2, ws);
    precompute_p2<<<1, 256, 0, stream>>>(
        (const unsigned int*)mask_cand, (const unsigned int*)mask_hist, ws);
  } else {
    precompute_fallback<<<1, 1024, 0, stream>>>(
        W1, W2, (const unsigned int*)mask_cand, (const unsigned int*)mask_hist, ws);
  }
  user_encoder_kernel<<<NB, 512, 0, stream>>>(hist, mask_cand, mask_hist, ws, out);
}